// Round 6
// baseline (782.507 us; speedup 1.0000x reference)
//
#include <hip/hip_runtime.h>

#define IN_HW 512
#define OUT_HW 1024
#define NB 32
#define NC 3
#define TOH 32
#define TOW 128
#define NTHREADS 256

typedef float  f32x4 __attribute__((ext_vector_type(4)));
typedef int    i32x4 __attribute__((ext_vector_type(4)));

// ---------------- sortable-key encoding for f32 atomics ----------------------
__device__ __forceinline__ unsigned enc_f(float f) {
  unsigned u = __float_as_uint(f);
  return (u & 0x80000000u) ? ~u : (u | 0x80000000u);
}
__device__ __forceinline__ float dec_f(unsigned k) {
  unsigned u = (k & 0x80000000u) ? (k ^ 0x80000000u) : ~k;
  return __uint_as_float(u);
}

// ---------------- hardcoded normalized Lanczos4 2x-upsample weights ----------
// Derived in f64: w(d)=sinc(d)sinc(d/4), phases d=3.75-j (even) / 3.25-j (odd),
// normalized to sum 1. Max abs error ~2e-6 -> output perturbation ~0.05 u8
// levels; cannot change absmax class.
#define LW_A -0.00397053f  /* |d|=3.75 */
#define LW_B  0.03146474f  /* |d|=2.75 */
#define LW_C -0.09165979f  /* |d|=1.75 */
#define LW_D  0.28268104f  /* |d|=0.75 */
#define LW_E  0.89337959f  /* |d|=0.25 */
#define LW_F -0.15228947f  /* |d|=1.25 */
#define LW_G  0.05544842f  /* |d|=2.25 */
#define LW_H -0.01505400f  /* |d|=3.25 */

// ---------------- kernel 0: init min/max key slots (ws is poisoned) ----------
__global__ void k_init(unsigned* __restrict__ maxk, unsigned* __restrict__ mink) {
  int i = threadIdx.x;
  if (i < NB) maxk[i] = 0u;
  else if (i < 2 * NB) mink[i - NB] = 0xFFFFFFFFu;
}

// ---------------- shared compute core: taps t[9][3] -> 2x8 outputs -----------
__device__ __forceinline__ void lanczos_core(const f32x4 t[9][3], float pr2[2][8]) {
  const float w0[8] = {LW_A, LW_B, LW_C, LW_D, LW_E, LW_F, LW_G, LW_H};
  const float w1[8] = {LW_H, LW_G, LW_F, LW_E, LW_D, LW_C, LW_B, LW_A};

  float ve[12], vo[12];
#pragma unroll
  for (int c = 0; c < 12; ++c) { ve[c] = 0.f; vo[c] = 0.f; }
#pragma unroll
  for (int j = 0; j < 9; ++j)
#pragma unroll
    for (int g = 0; g < 3; ++g)
#pragma unroll
      for (int c = 0; c < 4; ++c) {
        const float tv = t[j][g][c];
        if (j < 8) ve[4 * g + c] = fmaf(w0[j], tv, ve[4 * g + c]);
        if (j > 0) vo[4 * g + c] = fmaf(w1[j - 1], tv, vo[4 * g + c]);
      }

  // horizontal: even out col 2m taps v[m..m+7] (w0); odd taps v[m+1..m+8] (w1)
#pragma unroll
  for (int row = 0; row < 2; ++row) {
    const float* v = row ? vo : ve;
#pragma unroll
    for (int m = 0; m < 4; ++m) {
      float pe = 0.f, po = 0.f;
#pragma unroll
      for (int j = 0; j < 8; ++j) {
        pe = fmaf(w0[j], v[m + j], pe);
        po = fmaf(w1[j], v[m + 1 + j], po);
      }
      pr2[row][2 * m] = pe; pr2[row][2 * m + 1] = po;
    }
  }
}

// ---------------- interior fast path: no clamps, batched loads ---------------
// All 27 tap quads are loaded into registers BEFORE the vertical pass so the
// wave keeps ~27 independent 16B loads in flight (vs ~5 when interleaved with
// consumers) -- the prior version's 72% latency stall was Little's-law bound.
__device__ __forceinline__ void lanczos_tile_fast(
    const float* __restrict__ xchan, int row0p, int q0, float pr2[2][8]) {
  const float* __restrict__ tp = xchan + (size_t)row0p * IN_HW + 4 * q0;
  f32x4 t[9][3];
#pragma unroll
  for (int j = 0; j < 9; ++j)
#pragma unroll
    for (int g = 0; g < 3; ++g)
      t[j][g] = *reinterpret_cast<const f32x4*>(tp + j * IN_HW + 4 * g);
  lanczos_core(t, pr2);
}

// ---------------- general path: row clamp + column splat (borders) -----------
__device__ __forceinline__ void lanczos_tile_border(
    const float* __restrict__ xchan, int row0p, int qb, int o, float pr2[2][8]) {
  f32x4 t[9][3];
#pragma unroll
  for (int j = 0; j < 9; ++j) {
    int gr = row0p + j;
    gr = gr < 0 ? 0 : (gr > IN_HW - 1 ? IN_HW - 1 : gr);
    const float* __restrict__ rowp = xchan + ((size_t)gr << 9);
#pragma unroll
    for (int g = 0; g < 3; ++g) {
      const int q = qb + o + g;
      const int qc = q < 0 ? 0 : (q > IN_HW / 4 - 1 ? IN_HW / 4 - 1 : q);
      f32x4 v = reinterpret_cast<const f32x4*>(rowp)[qc];
      if (q < 0)             { float e = rowp[0];         v = (f32x4){e, e, e, e}; }
      if (q > IN_HW / 4 - 1) { float e = rowp[IN_HW - 1]; v = (f32x4){e, e, e, e}; }
      t[j][g] = v;
    }
  }
  lanczos_core(t, pr2);
}

// -------- kernel 1: resize ONCE -> f32 spill to out + per-image min/max ------
__global__ __launch_bounds__(NTHREADS) void k_resize(
    const float* __restrict__ x, float* __restrict__ outf,
    unsigned* __restrict__ maxk, unsigned* __restrict__ mink) {
  __shared__ float wred[8];
  const int tid = threadIdx.x;
  const int bc = blockIdx.z;
  const int oh0 = blockIdx.y * TOH, ow0 = blockIdx.x * TOW;
  const float* __restrict__ xchan = x + (size_t)bc * (IN_HW * IN_HW);
  const int o = tid & 15;
  const int p = tid >> 4;
  const int row0p = (oh0 >> 1) - 4 + p;
  const int qb = ((ow0 >> 1) - 4) >> 2;   // quad base (can be -1)

  // block-uniform: interior iff rows [row0..row0+23] and quads [qb..qb+17]
  // need no clamping -> x in [1,6], y in [1,30] (70% of blocks)
  const bool fast = (blockIdx.x > 0) & (blockIdx.x < 7) &
                    (blockIdx.y > 0) & (blockIdx.y < 31);
  float pr2[2][8];
  if (fast) lanczos_tile_fast(xchan, row0p, qb + o, pr2);
  else      lanczos_tile_border(xchan, row0p, qb, o, pr2);

  // spill f32 bits into the int32-per-pixel output buffer (pass 2 converts).
  // nontemporal: pass 2 is HBM-bound regardless; keep tap lines in L2.
  const size_t base = (size_t)bc * (OUT_HW * OUT_HW) +
                      (size_t)(oh0 + 2 * p) * OUT_HW + (ow0 + 8 * o);
#pragma unroll
  for (int row = 0; row < 2; ++row) {
    float* dst = outf + base + (size_t)row * OUT_HW;
    f32x4 lo = {pr2[row][0], pr2[row][1], pr2[row][2], pr2[row][3]};
    f32x4 hi = {pr2[row][4], pr2[row][5], pr2[row][6], pr2[row][7]};
    __builtin_nontemporal_store(lo, reinterpret_cast<f32x4*>(dst));
    __builtin_nontemporal_store(hi, reinterpret_cast<f32x4*>(dst + 4));
  }

  float mx = pr2[0][0], mn = pr2[0][0];
#pragma unroll
  for (int r = 0; r < 2; ++r)
#pragma unroll
    for (int i = 0; i < 8; ++i) {
      mx = fmaxf(mx, pr2[r][i]); mn = fminf(mn, pr2[r][i]);
    }
#pragma unroll
  for (int s = 32; s > 0; s >>= 1) {
    mx = fmaxf(mx, __shfl_xor(mx, s, 64));
    mn = fminf(mn, __shfl_xor(mn, s, 64));
  }
  if ((tid & 63) == 0) { wred[tid >> 6] = mx; wred[4 + (tid >> 6)] = mn; }
  __syncthreads();
  if (tid == 0) {
    float bmx = fmaxf(fmaxf(wred[0], wred[1]), fmaxf(wred[2], wred[3]));
    float bmn = fminf(fminf(wred[4], wred[5]), fminf(wred[6], wred[7]));
    int b = bc / NC;
    atomicMax(&maxk[b], enc_f(bmx));
    atomicMin(&mink[b], enc_f(bmn));
  }
}

// ---------------- kernel 2: in-place renorm f32 -> saturating int32 ----------
__device__ __forceinline__ int renorm1(float img, bool applies, float cA, float cB,
                                       float om_ott, float om_ubt) {
  const float ott = 1.0f / 255.0f;
  const float ubt = -10.0f / 255.0f;
  float v1 = (img > 1.0f) ? fmaf(img - 1.0f, cA, 1.0f - ott)
           : (img < 1.0f) ? img * om_ott : img;
  float v2 = (v1 < 0.0f) ? fmaf(v1, cB, ubt)
           : (v1 > 0.0f) ? v1 * om_ubt : v1;
  float y = (applies ? v2 : img) * 255.0f;
  int t = (int)y;                       // XLA f32->u8: trunc toward zero
  return t < 0 ? 0 : (t > 255 ? 255 : t);
}

#define N4_PER_IMG (NC * OUT_HW * OUT_HW / 4)   // 786432 float4 per image

__global__ __launch_bounds__(NTHREADS) void k_renorm(
    int* out, const unsigned* __restrict__ maxk, const unsigned* __restrict__ mink) {
  const int b = blockIdx.y;
  const float mx = dec_f(maxk[b]);
  const float mn = dec_f(mink[b]);
  const bool applies = (mx - mn) > 1.0f;
  const float ott = 1.0f / 255.0f;
  const float ubt = -10.0f / 255.0f;
  const float otr = mx - 1.0f;
  const float cA = ott / ((otr != 0.0f) ? otr : 1.0f);
  const float cB = ubt / ((mn != 0.0f) ? mn : 1.0f);
  const float om_ott = 1.0f - ott;
  const float om_ubt = 1.0f - ubt;

  const size_t idx = (size_t)b * N4_PER_IMG +
                     (size_t)blockIdx.x * NTHREADS + threadIdx.x;
  const f32x4 v = __builtin_nontemporal_load(
      reinterpret_cast<const f32x4*>(out) + idx);
  i32x4 r;
  r.x = renorm1(v.x, applies, cA, cB, om_ott, om_ubt);
  r.y = renorm1(v.y, applies, cA, cB, om_ott, om_ubt);
  r.z = renorm1(v.z, applies, cA, cB, om_ott, om_ubt);
  r.w = renorm1(v.w, applies, cA, cB, om_ott, om_ubt);
  __builtin_nontemporal_store(r, reinterpret_cast<i32x4*>(out) + idx);
}

extern "C" void kernel_launch(void* const* d_in, const int* in_sizes, int n_in,
                              void* d_out, int out_size, void* d_ws, size_t ws_size,
                              hipStream_t stream) {
  const float* x = (const float*)d_in[0];
  unsigned* maxk = (unsigned*)d_ws;
  unsigned* mink = maxk + NB;

  hipLaunchKernelGGL(k_init, dim3(1), dim3(64), 0, stream, maxk, mink);
  dim3 grid(OUT_HW / TOW, OUT_HW / TOH, NB * NC);
  hipLaunchKernelGGL(k_resize, grid, dim3(NTHREADS), 0, stream,
                     x, (float*)d_out, maxk, mink);
  hipLaunchKernelGGL(k_renorm, dim3(N4_PER_IMG / NTHREADS, NB), dim3(NTHREADS),
                     0, stream, (int*)d_out, maxk, mink);
}